// Round 3
// baseline (203.127 us; speedup 1.0000x reference)
//
#include <hip/hip_runtime.h>
#include <hip/hip_bf16.h>

// Quantumnet: pre-linear (B,512)->(B,3), tanh*pi/2, 3-qubit real statevector
// circuit, PauliZ expvals, post-linear (3->10). Inputs fp32 (R1 NaN proved
// bf16-reinterpretation is wrong); OUTPUT fp32 (R2's 3.93 absmax matches
// packed-bf16-read-as-fp32 scramble + unwritten second half). Sniffer kept
// as insurance on input dtype only.

#define F 512

__device__ __forceinline__ float bflo(unsigned u) { return __uint_as_float(u << 16); }
__device__ __forceinline__ float bfhi(unsigned u) { return __uint_as_float(u & 0xffff0000u); }
__device__ __forceinline__ float bfs(unsigned short v) { return __uint_as_float(((unsigned)v) << 16); }

__device__ __forceinline__ float fast_tanh(float x) {
    float e = __expf(2.0f * x);
    return 1.0f - 2.0f / (e + 1.0f);
}

// 8-element dot of fp32 LDS weights (16B-aligned) against unpacked inputs.
__device__ __forceinline__ float dot8(const float* __restrict__ w, const float* __restrict__ x) {
    float4 wa = ((const float4*)w)[0];
    float4 wb = ((const float4*)w)[1];
    float r;
    r = x[0] * wa.x;
    r = fmaf(x[1], wa.y, r);
    r = fmaf(x[2], wa.z, r);
    r = fmaf(x[3], wa.w, r);
    r = fmaf(x[4], wb.x, r);
    r = fmaf(x[5], wb.y, r);
    r = fmaf(x[6], wb.z, r);
    r = fmaf(x[7], wb.w, r);
    return r;
}

// RY 2x2 rotation on amplitude pair: RY = [[c,-s],[s,c]]
#define RYP(i0, i1, C, S) { float t0 = a[i0], t1 = a[i1]; \
    a[i0] = fmaf(-(S), t1, (C) * t0); \
    a[i1] = fmaf((S), t0, (C) * t1); }
#define SWAP(i, j) { float t = a[i]; a[i] = a[j]; a[j] = t; }

__global__ __launch_bounds__(256, 4) void qnet_kernel(
    const void* __restrict__ inp,    // (B,512)
    const void* __restrict__ preW,   // (3,512)
    const void* __restrict__ preB,   // (3,)
    const void* __restrict__ qp,     // (45,) rows 1,2 of (15,3) used
    const void* __restrict__ postW,  // (10,3)
    const void* __restrict__ postB,  // (10,)
    float* __restrict__ outp,        // (B,10) fp32
    int B)
{
    __shared__ __align__(16) float s_w[3 * F];
    __shared__ int s_cnt;

    const int tid = threadIdx.x;

    // ---- input dtype sniffer: fp32 randn -> low-16 exponent-field bits are
    // uniform (~16% in [100,140]); packed bf16 randn -> ~100%. Block-uniform.
    if (tid == 0) s_cnt = 0;
    __syncthreads();
    {
        unsigned w0 = ((const unsigned*)inp)[tid];      // first 1 KiB, safe either dtype
        unsigned lexp = (w0 >> 7) & 0xFFu;
        if (lexp >= 100u && lexp <= 140u) atomicAdd(&s_cnt, 1);
    }
    __syncthreads();
    const bool isbf = (s_cnt >= 128);

    // ---- stage pre_W into LDS as fp32 ----
    if (isbf) {
        for (int i = tid; i < 3 * F; i += 256) s_w[i] = bfs(((const unsigned short*)preW)[i]);
    } else {
        for (int i = tid; i < 3 * F; i += 256) s_w[i] = ((const float*)preW)[i];
    }
    __syncthreads();

    const int lane = tid & 63;
    const int wave = tid >> 6;
    const int c    = lane & 7;    // column-chunk lane (8 lanes per row)
    const int rsub = lane >> 3;   // row within wave's 8-row macro
    const int row  = (blockIdx.x * 4 + wave) * 8 + rsub;
    if (row >= B) return;

    // scalar param loader (dtype-agnostic)
    auto ldp = [&](const void* p, int i) -> float {
        return isbf ? bfs(((const unsigned short*)p)[i]) : ((const float*)p)[i];
    };

    // Trainable-layer trig (uniform across rows): q_weights[k+1, j], k=0,1
    float cw[6], sw[6];
#pragma unroll
    for (int k = 0; k < 2; ++k)
#pragma unroll
        for (int j = 0; j < 3; ++j) {
            float half_ang = ldp(qp, (k + 1) * 3 + j) * 0.5f;
            cw[k * 3 + j] = __cosf(half_ang);
            sw[k * 3 + j] = __sinf(half_ang);
        }

    // ---- pre-linear dot products ----
    float acc0 = 0.f, acc1 = 0.f, acc2 = 0.f;
    if (!isbf) {
        // fp32 path: lane c reads float4 chunks t*8+c; 8 lanes cover 128 B.
        const float4* __restrict__ xrow = (const float4*)((const float*)inp + (size_t)row * F);
#pragma unroll
        for (int t = 0; t < 16; ++t) {
            float4 xv = xrow[t * 8 + c];
            const int col = t * 32 + (c << 2);
            float4 w0 = *(const float4*)&s_w[col];
            float4 w1 = *(const float4*)&s_w[F + col];
            float4 w2 = *(const float4*)&s_w[2 * F + col];
            acc0 = fmaf(xv.x, w0.x, acc0); acc0 = fmaf(xv.y, w0.y, acc0);
            acc0 = fmaf(xv.z, w0.z, acc0); acc0 = fmaf(xv.w, w0.w, acc0);
            acc1 = fmaf(xv.x, w1.x, acc1); acc1 = fmaf(xv.y, w1.y, acc1);
            acc1 = fmaf(xv.z, w1.z, acc1); acc1 = fmaf(xv.w, w1.w, acc1);
            acc2 = fmaf(xv.x, w2.x, acc2); acc2 = fmaf(xv.y, w2.y, acc2);
            acc2 = fmaf(xv.z, w2.z, acc2); acc2 = fmaf(xv.w, w2.w, acc2);
        }
    } else {
        // bf16 path: lane c reads 8 bf16 (16 B) chunks t*8+c.
        const uint4* __restrict__ xrow = (const uint4*)((const unsigned short*)inp + (size_t)row * F);
#pragma unroll
        for (int t = 0; t < 8; ++t) {
            uint4 xv = xrow[t * 8 + c];
            float x[8];
            x[0] = bflo(xv.x); x[1] = bfhi(xv.x);
            x[2] = bflo(xv.y); x[3] = bfhi(xv.y);
            x[4] = bflo(xv.z); x[5] = bfhi(xv.z);
            x[6] = bflo(xv.w); x[7] = bfhi(xv.w);
            const int col = t * 64 + (c << 3);
            acc0 += dot8(&s_w[col],         x);
            acc1 += dot8(&s_w[F + col],     x);
            acc2 += dot8(&s_w[2 * F + col], x);
        }
    }
    // Reduce across the 8 column-lanes (xor bits 0..2 stay within the row group)
#pragma unroll
    for (int m = 1; m < 8; m <<= 1) {
        acc0 += __shfl_xor(acc0, m, 64);
        acc1 += __shfl_xor(acc1, m, 64);
        acc2 += __shfl_xor(acc2, m, 64);
    }

    // q_in = tanh(pre)*pi/2 ; RY half-angle = q_in/2 = tanh*pi/4
    const float PI4 = 0.7853981633974483f;
    float h0 = fast_tanh(acc0 + ldp(preB, 0)) * PI4;
    float h1 = fast_tanh(acc1 + ldp(preB, 1)) * PI4;
    float h2 = fast_tanh(acc2 + ldp(preB, 2)) * PI4;
    float c0 = __cosf(h0), s0 = __sinf(h0);
    float c1 = __cosf(h1), s1 = __sinf(h1);
    float c2 = __cosf(h2), s2 = __sinf(h2);

    // ---- statevector: |000> -> H^3 = uniform 1/sqrt(8) (real, RY-only circuit)
    float a[8];
#pragma unroll
    for (int i = 0; i < 8; ++i) a[i] = 0.35355339059327373f;

    // Encoding RY layer. wire0 acts on bit2 (pairs +-4), wire1 bit1, wire2 bit0.
    RYP(0, 4, c0, s0) RYP(1, 5, c0, s0) RYP(2, 6, c0, s0) RYP(3, 7, c0, s0)
    RYP(0, 2, c1, s1) RYP(1, 3, c1, s1) RYP(4, 6, c1, s1) RYP(5, 7, c1, s1)
    RYP(0, 1, c2, s2) RYP(2, 3, c2, s2) RYP(4, 5, c2, s2) RYP(6, 7, c2, s2)

#pragma unroll
    for (int k = 0; k < 2; ++k) {
        // CNOT01 (ctrl bit2, tgt bit1): swap 4<->6, 5<->7
        SWAP(4, 6) SWAP(5, 7)
        // CNOT12 (ctrl bit1, tgt bit0): swap 2<->3, 6<->7
        SWAP(2, 3) SWAP(6, 7)
        float kc0 = cw[k * 3 + 0], ks0 = sw[k * 3 + 0];
        float kc1 = cw[k * 3 + 1], ks1 = sw[k * 3 + 1];
        float kc2 = cw[k * 3 + 2], ks2 = sw[k * 3 + 2];
        RYP(0, 4, kc0, ks0) RYP(1, 5, kc0, ks0) RYP(2, 6, kc0, ks0) RYP(3, 7, kc0, ks0)
        RYP(0, 2, kc1, ks1) RYP(1, 3, kc1, ks1) RYP(4, 6, kc1, ks1) RYP(5, 7, kc1, ks1)
        RYP(0, 1, kc2, ks2) RYP(2, 3, kc2, ks2) RYP(4, 5, kc2, ks2) RYP(6, 7, kc2, ks2)
    }

    // PauliZ expectations from probabilities
    float p[8];
#pragma unroll
    for (int i = 0; i < 8; ++i) p[i] = a[i] * a[i];
    float e0 = (p[0] + p[1] + p[2] + p[3]) - (p[4] + p[5] + p[6] + p[7]);
    float e1 = (p[0] + p[1] + p[4] + p[5]) - (p[2] + p[3] + p[6] + p[7]);
    float e2 = (p[0] + p[2] + p[4] + p[6]) - (p[1] + p[3] + p[5] + p[7]);

    // Post-linear: lane c<5 writes outputs (2c, 2c+1) as float2 (fp32 out).
    if (c < 5) {
        int n0 = 2 * c, n1 = 2 * c + 1;
        float o0 = ldp(postB, n0);
        o0 = fmaf(e0, ldp(postW, n0 * 3 + 0), o0);
        o0 = fmaf(e1, ldp(postW, n0 * 3 + 1), o0);
        o0 = fmaf(e2, ldp(postW, n0 * 3 + 2), o0);
        float o1 = ldp(postB, n1);
        o1 = fmaf(e0, ldp(postW, n1 * 3 + 0), o1);
        o1 = fmaf(e1, ldp(postW, n1 * 3 + 1), o1);
        o1 = fmaf(e2, ldp(postW, n1 * 3 + 2), o1);
        float2 pair = make_float2(o0, o1);
        ((float2*)outp)[(size_t)row * 5 + c] = pair;
    }
}

extern "C" void kernel_launch(void* const* d_in, const int* in_sizes, int n_in,
                              void* d_out, int out_size, void* d_ws, size_t ws_size,
                              hipStream_t stream) {
    int B = in_sizes[0] / F;          // 65536
    int waves = (B + 7) / 8;          // 8 rows per wave
    int blocks = (waves + 3) / 4;     // 4 waves per block -> 2048
    qnet_kernel<<<blocks, 256, 0, stream>>>(
        d_in[0], d_in[1], d_in[2], d_in[3], d_in[4], d_in[5],
        (float*)d_out, B);
}

// Round 4
// 187.104 us; speedup vs baseline: 1.0856x; 1.0856x over previous
//
#include <hip/hip_runtime.h>
#include <hip/hip_bf16.h>

// Quantumnet: pre-linear (B,512)->(B,3) fp32, tanh*pi/2, 3-qubit real
// statevector circuit (RY-only => real amplitudes), PauliZ expvals,
// post-linear (3->10), fp32 out.
// Dtypes settled by R1-R3 evidence: fp32 in (R1 bf16-reinterp -> NaN),
// fp32 out (R3 passed, absmax 7.8e-3). Memory-bound: 128 MiB X read once.
// Kernel floor ~20 us; headline dur_us is dominated by harness d_ws poison
// fills (2x512 MiB @ ~77 us) + d_in restore, which we cannot control.

#define F 512

typedef float v4f __attribute__((ext_vector_type(4)));

__device__ __forceinline__ float fast_tanh(float x) {
    float e = __expf(2.0f * x);
    return 1.0f - 2.0f / (e + 1.0f);
}

// RY 2x2 rotation on amplitude pair: RY = [[c,-s],[s,c]]
#define RYP(i0, i1, C, S) { float t0 = a[i0], t1 = a[i1]; \
    a[i0] = fmaf(-(S), t1, (C) * t0); \
    a[i1] = fmaf((S), t0, (C) * t1); }
#define SWAP(i, j) { float t = a[i]; a[i] = a[j]; a[j] = t; }

__global__ __launch_bounds__(256, 4) void qnet_kernel(
    const float* __restrict__ inp,    // (B,512) fp32
    const float* __restrict__ preW,   // (3,512)
    const float* __restrict__ preB,   // (3,)
    const float* __restrict__ qp,     // (45,) rows 1,2 of (15,3) used
    const float* __restrict__ postW,  // (10,3)
    const float* __restrict__ postB,  // (10,)
    float* __restrict__ outp,         // (B,10) fp32
    int B)
{
    __shared__ __align__(16) float s_w[3 * F];

    const int tid = threadIdx.x;

    // ---- stage pre_W into LDS (6 KB), float4-vectorized, once per block ----
    {
        const v4f* __restrict__ src = (const v4f*)preW;
        v4f* dst = (v4f*)s_w;
        for (int i = tid; i < 3 * F / 4; i += 256) dst[i] = src[i];
    }
    __syncthreads();

    const int lane = tid & 63;
    const int wave = tid >> 6;
    const int c    = lane & 7;    // column-chunk lane (8 lanes per row)
    const int rsub = lane >> 3;   // row within wave's 8-row macro
    const int row  = (blockIdx.x * 4 + wave) * 8 + rsub;
    if (row >= B) return;

    // Trainable-layer trig (uniform across rows): q_weights[k+1, j], k=0,1
    float cw[6], sw[6];
#pragma unroll
    for (int k = 0; k < 2; ++k)
#pragma unroll
        for (int j = 0; j < 3; ++j) {
            float half_ang = qp[(k + 1) * 3 + j] * 0.5f;
            cw[k * 3 + j] = __cosf(half_ang);
            sw[k * 3 + j] = __sinf(half_ang);
        }

    // ---- pre-linear dots: lane c reads float4 chunks t*8+c (coalesced,
    // 8 rows x 128 B per wave instruction). Nontemporal: X is read-once.
    const v4f* __restrict__ xrow = (const v4f*)(inp + (size_t)row * F);
    float acc0 = 0.f, acc1 = 0.f, acc2 = 0.f;
#pragma unroll
    for (int t = 0; t < 16; ++t) {
        v4f xv = __builtin_nontemporal_load(&xrow[t * 8 + c]);
        const int col = t * 32 + (c << 2);
        v4f w0 = *(const v4f*)&s_w[col];
        v4f w1 = *(const v4f*)&s_w[F + col];
        v4f w2 = *(const v4f*)&s_w[2 * F + col];
        acc0 = fmaf(xv.x, w0.x, acc0); acc0 = fmaf(xv.y, w0.y, acc0);
        acc0 = fmaf(xv.z, w0.z, acc0); acc0 = fmaf(xv.w, w0.w, acc0);
        acc1 = fmaf(xv.x, w1.x, acc1); acc1 = fmaf(xv.y, w1.y, acc1);
        acc1 = fmaf(xv.z, w1.z, acc1); acc1 = fmaf(xv.w, w1.w, acc1);
        acc2 = fmaf(xv.x, w2.x, acc2); acc2 = fmaf(xv.y, w2.y, acc2);
        acc2 = fmaf(xv.z, w2.z, acc2); acc2 = fmaf(xv.w, w2.w, acc2);
    }
    // Reduce across the 8 column-lanes (xor bits 0..2 stay within the row group)
#pragma unroll
    for (int m = 1; m < 8; m <<= 1) {
        acc0 += __shfl_xor(acc0, m, 64);
        acc1 += __shfl_xor(acc1, m, 64);
        acc2 += __shfl_xor(acc2, m, 64);
    }

    // q_in = tanh(pre)*pi/2 ; RY half-angle = q_in/2 = tanh*pi/4
    const float PI4 = 0.7853981633974483f;
    float h0 = fast_tanh(acc0 + preB[0]) * PI4;
    float h1 = fast_tanh(acc1 + preB[1]) * PI4;
    float h2 = fast_tanh(acc2 + preB[2]) * PI4;
    float c0 = __cosf(h0), s0 = __sinf(h0);
    float c1 = __cosf(h1), s1 = __sinf(h1);
    float c2 = __cosf(h2), s2 = __sinf(h2);

    // ---- statevector: |000> -> H^3 = uniform 1/sqrt(8) (real, RY-only)
    float a[8];
#pragma unroll
    for (int i = 0; i < 8; ++i) a[i] = 0.35355339059327373f;

    // Encoding RY layer. wire0 acts on bit2 (pairs +-4), wire1 bit1, wire2 bit0.
    RYP(0, 4, c0, s0) RYP(1, 5, c0, s0) RYP(2, 6, c0, s0) RYP(3, 7, c0, s0)
    RYP(0, 2, c1, s1) RYP(1, 3, c1, s1) RYP(4, 6, c1, s1) RYP(5, 7, c1, s1)
    RYP(0, 1, c2, s2) RYP(2, 3, c2, s2) RYP(4, 5, c2, s2) RYP(6, 7, c2, s2)

#pragma unroll
    for (int k = 0; k < 2; ++k) {
        // CNOT01 (ctrl bit2, tgt bit1): swap 4<->6, 5<->7
        SWAP(4, 6) SWAP(5, 7)
        // CNOT12 (ctrl bit1, tgt bit0): swap 2<->3, 6<->7
        SWAP(2, 3) SWAP(6, 7)
        float kc0 = cw[k * 3 + 0], ks0 = sw[k * 3 + 0];
        float kc1 = cw[k * 3 + 1], ks1 = sw[k * 3 + 1];
        float kc2 = cw[k * 3 + 2], ks2 = sw[k * 3 + 2];
        RYP(0, 4, kc0, ks0) RYP(1, 5, kc0, ks0) RYP(2, 6, kc0, ks0) RYP(3, 7, kc0, ks0)
        RYP(0, 2, kc1, ks1) RYP(1, 3, kc1, ks1) RYP(4, 6, kc1, ks1) RYP(5, 7, kc1, ks1)
        RYP(0, 1, kc2, ks2) RYP(2, 3, kc2, ks2) RYP(4, 5, kc2, ks2) RYP(6, 7, kc2, ks2)
    }

    // PauliZ expectations from probabilities
    float p[8];
#pragma unroll
    for (int i = 0; i < 8; ++i) p[i] = a[i] * a[i];
    float e0 = (p[0] + p[1] + p[2] + p[3]) - (p[4] + p[5] + p[6] + p[7]);
    float e1 = (p[0] + p[1] + p[4] + p[5]) - (p[2] + p[3] + p[6] + p[7]);
    float e2 = (p[0] + p[2] + p[4] + p[6]) - (p[1] + p[3] + p[5] + p[7]);

    // Post-linear: lane c<5 writes outputs (2c, 2c+1) as float2.
    if (c < 5) {
        int n0 = 2 * c, n1 = 2 * c + 1;
        float o0 = postB[n0];
        o0 = fmaf(e0, postW[n0 * 3 + 0], o0);
        o0 = fmaf(e1, postW[n0 * 3 + 1], o0);
        o0 = fmaf(e2, postW[n0 * 3 + 2], o0);
        float o1 = postB[n1];
        o1 = fmaf(e0, postW[n1 * 3 + 0], o1);
        o1 = fmaf(e1, postW[n1 * 3 + 1], o1);
        o1 = fmaf(e2, postW[n1 * 3 + 2], o1);
        float2 pair = make_float2(o0, o1);
        ((float2*)outp)[(size_t)row * 5 + c] = pair;
    }
}

extern "C" void kernel_launch(void* const* d_in, const int* in_sizes, int n_in,
                              void* d_out, int out_size, void* d_ws, size_t ws_size,
                              hipStream_t stream) {
    int B = in_sizes[0] / F;          // 65536
    int waves = (B + 7) / 8;          // 8 rows per wave
    int blocks = (waves + 3) / 4;     // 4 waves per block -> 2048
    qnet_kernel<<<blocks, 256, 0, stream>>>(
        (const float*)d_in[0], (const float*)d_in[1], (const float*)d_in[2],
        (const float*)d_in[3], (const float*)d_in[4], (const float*)d_in[5],
        (float*)d_out, B);
}